// Round 15
// baseline (332.770 us; speedup 1.0000x reference)
//
#include <hip/hip_runtime.h>
#include <hip/hip_bf16.h>

#define B_ 256
#define N_ 256
#define H_ 16
// softmax scale folded with log2(e); bias folded with log2(e)
#define SCALE2_ 0.25504526484f   // (1/sqrt(32)) * log2(e)
#define LOG2E_ 1.4426950408889634f

typedef __attribute__((ext_vector_type(8))) short short8;
typedef __attribute__((ext_vector_type(4))) float f32x4v;
typedef unsigned int u32;

// async global->LDS, 16B per lane. LDS dest must be wave-uniform base (+lane*16).
#define GLOAD16(gptr, lptr)                                                        \
  __builtin_amdgcn_global_load_lds((const __attribute__((address_space(1))) u32*)(gptr), \
                                   (__attribute__((address_space(3))) u32*)(lptr), 16, 0, 0)

static __device__ __forceinline__ unsigned cvt_pk_bf16(float lo, float hi) {
  unsigned r;
  asm("v_cvt_pk_bf16_f32 %0, %1, %2" : "=v"(r) : "v"(lo), "v"(hi));
  return r;
}

// K0: fused prep — blocks [0,192): temb_mod (tiled 4b x 512cols);
// [192,1216): cvt_x; [1216,1472): W transposes.
// temb_mod tiling note: the old 1-b-per-block layout read ALL of temb_w per
// block (256 x 3MB = 768 MB through L2/L3, ~55us + tail imbalance). This
// tiling reads each 1MB col-chunk 64x (192 MB, L2-resident) with identical
// per-output f32 summation order (bit-exact vs reference path).
__global__ __launch_bounds__(512)
void prep_kernel(const float* __restrict__ temb, const float* __restrict__ temb_w,
                 const float* __restrict__ temb_b, const float* __restrict__ qkv_b,
                 float* __restrict__ tm,
                 const float* __restrict__ x, unsigned* __restrict__ xb16,
                 const float* __restrict__ qkv_w, unsigned short* __restrict__ qkv_wT,
                 const float* __restrict__ proj_w, unsigned short* __restrict__ proj_wT) {
  __shared__ __align__(16) char lbuf[17024];
  const int blk = blockIdx.x;
  const int t = threadIdx.x;

  if (blk < 192) {
    // ---- temb_mod: tm[b][c] = temb[b]@temb_w[:,c] + temb_b[c] + qkv_b[c] ----
    // block: 4 batches x 512 cols. thread: 1 batch x 4 consecutive cols.
    float (*ts)[512] = (float (*)[512])lbuf;      // 4 x 512 f32 = 8 KB
    const int b0 = (blk / 3) << 2;
    const int c0 = (blk % 3) << 9;
    {
#pragma unroll
      for (int i = 0; i < 4; ++i) {
        const int idx = t + i * 512;
        ts[idx >> 9][idx & 511] = temb[(size_t)b0 * 512 + idx];
      }
    }
    __syncthreads();
    const int bl = t >> 7;                 // 0..3
    const int c4 = c0 + ((t & 127) << 2);  // col of this thread's float4
    float4 acc;
    {
      const float4 tb4 = *reinterpret_cast<const float4*>(temb_b + c4);
      const float4 qb4 = *reinterpret_cast<const float4*>(qkv_b + c4);
      acc.x = tb4.x + qb4.x; acc.y = tb4.y + qb4.y;
      acc.z = tb4.z + qb4.z; acc.w = tb4.w + qb4.w;
    }
#pragma unroll 4
    for (int k = 0; k < 512; ++k) {
      const float tv = ts[bl][k];
      const float4 wv = *reinterpret_cast<const float4*>(temb_w + (size_t)k * 1536 + c4);
      acc.x += tv * wv.x; acc.y += tv * wv.y;
      acc.z += tv * wv.z; acc.w += tv * wv.w;
    }
    *reinterpret_cast<float4*>(tm + (size_t)(b0 + bl) * 1536 + c4) = acc;
  } else if (blk < 1216) {
    // ---- cvt_x: f32 -> bf16, 8 elems/thread/iter ----
    const int n8 = (B_ * N_ * 512) / 8;
    int i = (blk - 192) * 512 + t;
    for (; i < n8; i += 1024 * 512) {
      const float4* p = reinterpret_cast<const float4*>(x + (size_t)i * 8);
      float4 a = p[0], b4 = p[1];
      uint4 vv = make_uint4(cvt_pk_bf16(a.x, a.y), cvt_pk_bf16(a.z, a.w),
                            cvt_pk_bf16(b4.x, b4.y), cvt_pk_bf16(b4.z, b4.w));
      *reinterpret_cast<uint4*>(xb16 + (size_t)i * 4) = vv;
    }
  } else {
    // ---- transpose+convert W [512][ncols] f32 -> WT [ncols][512] bf16 ----
    const float* src; unsigned short* dst; int ncols, k0, n0;
    if (blk < 1408) {
      const int idx = blk - 1216;           // 16 k-blocks x 12 n-blocks
      src = qkv_w; dst = qkv_wT; ncols = 1536;
      k0 = (idx / 12) << 5; n0 = (idx % 12) << 7;
    } else {
      const int idx = blk - 1408;           // 16 x 4
      src = proj_w; dst = proj_wT; ncols = 512;
      k0 = (idx >> 2) << 5; n0 = (idx & 3) << 7;
    }
    float (*tile)[133] = (float (*)[133])lbuf;   // 32 x 128 tile, pad 133
    {
      const int kk = t >> 4, c0 = (t & 15) << 3;
      const float* s = src + (size_t)(k0 + kk) * ncols + n0 + c0;
      float4 v0 = *reinterpret_cast<const float4*>(s);
      float4 v1 = *reinterpret_cast<const float4*>(s + 4);
      tile[kk][c0 + 0] = v0.x; tile[kk][c0 + 1] = v0.y; tile[kk][c0 + 2] = v0.z; tile[kk][c0 + 3] = v0.w;
      tile[kk][c0 + 4] = v1.x; tile[kk][c0 + 5] = v1.y; tile[kk][c0 + 6] = v1.z; tile[kk][c0 + 7] = v1.w;
    }
    __syncthreads();
    {
      const int nn = t >> 2, ck = (t & 3) << 3;
      uint4 vv = make_uint4(cvt_pk_bf16(tile[ck + 0][nn], tile[ck + 1][nn]),
                            cvt_pk_bf16(tile[ck + 2][nn], tile[ck + 3][nn]),
                            cvt_pk_bf16(tile[ck + 4][nn], tile[ck + 5][nn]),
                            cvt_pk_bf16(tile[ck + 6][nn], tile[ck + 7][nn]));
      *reinterpret_cast<uint4*>(dst + (size_t)(n0 + nn) * 512 + k0 + ck) = vv;
    }
  }
}

// K1: fused qkv-GEMM + flash attention per (b,h). 512 thr, 8 waves.
// Phase A: 3-buffer gload_lds staging with counted-vmcnt raw barriers (r10/r12
// version, measured 196us). r11 (f32 reg-stage x) and r13 (W direct-to-reg,
// barrier-free) both regressed: any operand consumed same-iteration must come
// from LDS staged >=1 iter ahead — scattered global->reg loads with zero
// lookahead serialize L2 latency into every k-step.
// Flash: NO online max, bias as MFMA C-input, lsum via ones-B MFMA, rcp.
// __launch_bounds__(512,4): 128-reg budget; waves=6 spilled (r3/r4 lesson).
__global__ __launch_bounds__(512, 4)
void fused_attn_kernel(const unsigned short* __restrict__ xb16,   // [65536][512]
                       const unsigned short* __restrict__ wT,     // [1536][512]
                       const float* __restrict__ rpb,
                       const float* __restrict__ tm,
                       unsigned short* __restrict__ attn_out) {
  // bytes: x-stage x3 [0,49152) | W-stage x3 [49152,67584)
  // after phase A: qs [0,16384), ks [16384,32768), vTs [32768,49152), bias [49152,53000)
  __shared__ __align__(16) char smem[67584];
  short* xs     = (short*)smem;             // x buffers / qs
  short* ksp    = (short*)(smem + 16384);   // ks (persistent)
  short* vTs    = (short*)(smem + 32768);   // vTs (persistent)
  short* wstage = (short*)(smem + 49152);   // W buffers x3
  float* biasT  = (float*)(smem + 49152);   // bias (after staging dead)

  // bijective XCD remap: blockIdx%8 ~ XCD; give each XCD 32 consecutive b
  const int u = blockIdx.x;
  const int bh = ((u & 7) << 9) | (u >> 3);
  const int b = bh >> 4, h = bh & 15;
  const int tid = threadIdx.x;
  const int w = tid >> 6, l = tid & 63;
  const int l16 = l & 15, g = l >> 4;
  const int gsw8 = (g ^ ((l16 >> 1) & 3)) << 3;          // swizzled frag offset (shorts)
  const int lrow = l >> 2;
  const int lcol = (((l & 3) ^ ((l >> 3) & 3)) << 3);    // swizzled source col

  const unsigned short* xsrc0 = xb16 + (size_t)(b * 256 + w * 16 + lrow) * 512 + lcol;
  const unsigned short* xsrc1 = xsrc0 + (size_t)128 * 512;
  const int row96 = w * 16 + lrow;
  const unsigned short* wsrc = wT + (size_t)((row96 >> 5) * 512 + h * 32 + (row96 & 31)) * 512 + lcol;

  f32x4v acc[2][6];
#pragma unroll
  for (int mt = 0; mt < 2; ++mt)
#pragma unroll
    for (int nt = 0; nt < 6; ++nt) acc[mt][nt] = (f32x4v)(0.0f);

  // ---- Phase A (3-buf, counted-vmcnt single barrier per k-tile) ----
  auto stage = [&](int t, int bufi) {
    const int k0 = t << 5;
    GLOAD16(xsrc0 + k0, xs + bufi * 8192 + w * 512);
    GLOAD16(xsrc1 + k0, xs + bufi * 8192 + (8 + w) * 512);
    if (w < 6) GLOAD16(wsrc + k0, wstage + bufi * 3072 + w * 512);
  };
  stage(0, 0);
#pragma unroll
  for (int t = 0; t < 16; ++t) {
    const int buf = t % 3;
    if (t < 15) {
      stage(t + 1, (t + 1) % 3);
      if (w < 6) asm volatile("s_waitcnt vmcnt(3)" ::: "memory");
      else       asm volatile("s_waitcnt vmcnt(2)" ::: "memory");
    } else {
      asm volatile("s_waitcnt vmcnt(0)" ::: "memory");
    }
    __builtin_amdgcn_sched_barrier(0);
    __builtin_amdgcn_s_barrier();
    __builtin_amdgcn_sched_barrier(0);
    short* xb = xs + buf * 8192;
    short* wb = wstage + buf * 3072;
    short8 af[2], bfr[6];
#pragma unroll
    for (int mt = 0; mt < 2; ++mt)
      af[mt] = *reinterpret_cast<short8*>(&xb[(w * 32 + mt * 16 + l16) * 32 + gsw8]);
#pragma unroll
    for (int nt = 0; nt < 6; ++nt)
      bfr[nt] = *reinterpret_cast<short8*>(&wb[(nt * 16 + l16) * 32 + gsw8]);
#pragma unroll
    for (int mt = 0; mt < 2; ++mt)
#pragma unroll
      for (int nt = 0; nt < 6; ++nt)
        acc[mt][nt] = __builtin_amdgcn_mfma_f32_16x16x32_bf16(af[mt], bfr[nt], acc[mt][nt], 0, 0, 0);
  }
  __syncthreads();   // all reads done before epilogue overwrites staging regions

  // ---- epilogue A: +tm bias; q (log2-scaled) -> xs, k -> ksp, v -> vTs ----
  const float* tmb = tm + (size_t)b * 1536 + h * 32;
#pragma unroll
  for (int nt = 0; nt < 6; ++nt) {
    const int prt = nt >> 1;
    const int d = ((nt & 1) << 4) + l16;
    const float tmv = tmb[(prt << 9) + d];
#pragma unroll
    for (int mt = 0; mt < 2; ++mt) {
      const int r0 = w * 32 + mt * 16 + g * 4;
      float v0 = acc[mt][nt][0] + tmv, v1 = acc[mt][nt][1] + tmv;
      float v2 = acc[mt][nt][2] + tmv, v3 = acc[mt][nt][3] + tmv;
      if (prt == 0) { v0 *= SCALE2_; v1 *= SCALE2_; v2 *= SCALE2_; v3 *= SCALE2_; }
      const u32 p01 = cvt_pk_bf16(v0, v1);
      const u32 p23 = cvt_pk_bf16(v2, v3);
      if (prt != 2) {
        short* dst = (prt == 0) ? xs : ksp;
        const int unit01 = ((d >> 3) ^ ((r0 >> 1) & 3)) << 3;
        const int base = r0 * 32 + unit01 + (d & 7);
        // rows r0,r0+1 share unit; r0+2,r0+3 have unit^1 (r0 ≡ 0 mod 4)
        dst[base]            = (short)p01;
        dst[base + 32]       = (short)(p01 >> 16);
        dst[(base + 64) ^ 8] = (short)p23;
        dst[(base + 96) ^ 8] = (short)(p23 >> 16);
      } else {
#pragma unroll
        for (int j = 0; j < 4; ++j) {
          const int key = r0 + j;
          const int vcol = ((key >> 5) << 5) | (((key & 15) << 1) | ((key >> 4) & 1));
          const int unit = ((vcol >> 3) ^ (d & 7));
          const u32 pk = (j < 2) ? p01 : p23;
          vTs[d * 256 + (unit << 3) + (vcol & 7)] = (short)(pk >> ((j & 1) << 4));
        }
      }
    }
  }
  for (int e = tid; e < 961; e += 512) biasT[e] = rpb[e * 16 + h] * LOG2E_;
  __syncthreads();

  // ---- flash attention: S^T = mfma(K, Q, C=bias); P in registers; no max ----
  short8 bq[2];
#pragma unroll
  for (int mt = 0; mt < 2; ++mt)
    bq[mt] = *reinterpret_cast<short8*>(&xs[(w * 32 + mt * 16 + l16) * 32 + gsw8]);

  const int bcol = l16 - (g << 2) + 15;    // [0,30]
  const int brow0 = w * 2 + 15;

  f32x4v bp_prev;
#pragma unroll
  for (int j = 0; j < 4; ++j) bp_prev[j] = biasT[(brow0 + 1) * 31 + bcol - j];

  // all-ones bf16 B-fragment for the lsum MFMA
  short8 ones8;
#pragma unroll
  for (int j = 0; j < 8; ++j) ones8[j] = (short)0x3F80;

  f32x4v oacc[2][2];
  f32x4v oaccL[2];
#pragma unroll
  for (int mt = 0; mt < 2; ++mt) {
    oacc[mt][0] = (f32x4v)(0.0f);
    oacc[mt][1] = (f32x4v)(0.0f);
    oaccL[mt] = (f32x4v)(0.0f);
  }

#pragma unroll
  for (int kc = 0; kc < 8; ++kc) {
    const int kt0 = kc * 2, kt1 = kc * 2 + 1;
    short8 kf0 = *reinterpret_cast<short8*>(&ksp[(kt0 * 16 + l16) * 32 + gsw8]);
    short8 kf1 = *reinterpret_cast<short8*>(&ksp[(kt1 * 16 + l16) * 32 + gsw8]);
    f32x4v cA, cB;
    const float* brA = biasT + (brow0 - kt0) * 31 + bcol;
    const float* brB = biasT + (brow0 - kt1) * 31 + bcol;
#pragma unroll
    for (int j = 0; j < 4; ++j) { cA[j] = brA[-j]; cB[j] = brB[-j]; }
    f32x4v s00, s01, s10, s11;   // s[ct][mt]
    __builtin_amdgcn_s_setprio(1);
    s00 = __builtin_amdgcn_mfma_f32_16x16x32_bf16(kf0, bq[0], cA, 0, 0, 0);
    s01 = __builtin_amdgcn_mfma_f32_16x16x32_bf16(kf0, bq[1], bp_prev, 0, 0, 0);
    s10 = __builtin_amdgcn_mfma_f32_16x16x32_bf16(kf1, bq[0], cB, 0, 0, 0);
    s11 = __builtin_amdgcn_mfma_f32_16x16x32_bf16(kf1, bq[1], cA, 0, 0, 0);
    __builtin_amdgcn_s_setprio(0);
    bp_prev = cB;

    short8 pa0, pa1;
    {
      union { u32 u[4]; short8 s8; } pk0, pk1;
#pragma unroll
      for (int j = 0; j < 4; ++j) {
        pk0.u[j] = cvt_pk_bf16(exp2f(s00[j]), exp2f(s10[j]));
        pk1.u[j] = cvt_pk_bf16(exp2f(s01[j]), exp2f(s11[j]));
      }
      pa0 = pk0.s8; pa1 = pk1.s8;
    }
    short8 bv0 = *reinterpret_cast<short8*>(
        &vTs[(l16) * 256 + ((((kc * 4 + g) ^ (l16 & 7)) << 3))]);
    short8 bv1 = *reinterpret_cast<short8*>(
        &vTs[(16 + l16) * 256 + ((((kc * 4 + g) ^ (l16 & 7)) << 3))]);
    __builtin_amdgcn_s_setprio(1);
    oacc[0][0] = __builtin_amdgcn_mfma_f32_16x16x32_bf16(pa0, bv0, oacc[0][0], 0, 0, 0);
    oacc[0][1] = __builtin_amdgcn_mfma_f32_16x16x32_bf16(pa0, bv1, oacc[0][1], 0, 0, 0);
    oacc[1][0] = __builtin_amdgcn_mfma_f32_16x16x32_bf16(pa1, bv0, oacc[1][0], 0, 0, 0);
    oacc[1][1] = __builtin_amdgcn_mfma_f32_16x16x32_bf16(pa1, bv1, oacc[1][1], 0, 0, 0);
    oaccL[0]   = __builtin_amdgcn_mfma_f32_16x16x32_bf16(pa0, ones8, oaccL[0], 0, 0, 0);
    oaccL[1]   = __builtin_amdgcn_mfma_f32_16x16x32_bf16(pa1, ones8, oaccL[1], 0, 0, 0);
    __builtin_amdgcn_s_setprio(0);
  }

  // ---- normalize (lsum already in-lane via ones-MFMA), bounce O, store ----
  float i0[4], i1[4];
#pragma unroll
  for (int j = 0; j < 4; ++j) {
    i0[j] = __builtin_amdgcn_rcpf(oaccL[0][j]);
    i1[j] = __builtin_amdgcn_rcpf(oaccL[1][j]);
  }
  short* ob = xs + w * 1024;   // own wave's 32x32 region, dead after bq load
  const int u0 = (((l16 >> 3) ^ g) << 3) + (l16 & 7);
  const int u1 = ((((l16 >> 3) | 2) ^ g) << 3) + (l16 & 7);
  {
    const u32 a01 = cvt_pk_bf16(oacc[0][0][0] * i0[0], oacc[0][0][1] * i0[1]);
    const u32 a23 = cvt_pk_bf16(oacc[0][0][2] * i0[2], oacc[0][0][3] * i0[3]);
    const u32 b01 = cvt_pk_bf16(oacc[0][1][0] * i0[0], oacc[0][1][1] * i0[1]);
    const u32 b23 = cvt_pk_bf16(oacc[0][1][2] * i0[2], oacc[0][1][3] * i0[3]);
    const u32 c01 = cvt_pk_bf16(oacc[1][0][0] * i1[0], oacc[1][0][1] * i1[1]);
    const u32 c23 = cvt_pk_bf16(oacc[1][0][2] * i1[2], oacc[1][0][3] * i1[3]);
    const u32 d01 = cvt_pk_bf16(oacc[1][1][0] * i1[0], oacc[1][1][1] * i1[1]);
    const u32 d23 = cvt_pk_bf16(oacc[1][1][2] * i1[2], oacc[1][1][3] * i1[3]);
    const int r0 = (g << 2) * 32;
    ob[r0 + u0]       = (short)a01;  ob[r0 + 32 + u0]  = (short)(a01 >> 16);
    ob[r0 + 64 + u0]  = (short)a23;  ob[r0 + 96 + u0]  = (short)(a23 >> 16);
    ob[r0 + u1]       = (short)b01;  ob[r0 + 32 + u1]  = (short)(b01 >> 16);
    ob[r0 + 64 + u1]  = (short)b23;  ob[r0 + 96 + u1]  = (short)(b23 >> 16);
    const int r1 = r0 + 512;
    ob[r1 + u0]       = (short)c01;  ob[r1 + 32 + u0]  = (short)(c01 >> 16);
    ob[r1 + 64 + u0]  = (short)c23;  ob[r1 + 96 + u0]  = (short)(c23 >> 16);
    ob[r1 + u1]       = (short)d01;  ob[r1 + 32 + u1]  = (short)(d01 >> 16);
    ob[r1 + 64 + u1]  = (short)d23;  ob[r1 + 96 + u1]  = (short)(d23 >> 16);
  }
  // own-wave region: no barrier needed (compiler orders ds_write->ds_read)
  unsigned short* aw = attn_out + (size_t)(b * 256 + w * 32) * 512 + h * 32;
#pragma unroll
  for (int i = 0; i < 2; ++i) {
    const int r = i * 16 + (l >> 2);
    const int cu = l & 3;
    const int su = cu ^ ((r >> 2) & 3);
    short8 vv = *reinterpret_cast<short8*>(&ob[r * 32 + (su << 3)]);
    *reinterpret_cast<short8*>(aw + (size_t)r * 512 + (cu << 3)) = vv;
  }
}

// K2: out = attn @ proj_wT^T + proj_b  (2-buf, issue-after-barrier counted scheme)
__global__ __launch_bounds__(256)
void proj_kernel(const unsigned short* __restrict__ A,    // [65536][512] bf16
                 const unsigned short* __restrict__ BT,   // [512][512] bf16
                 const float* __restrict__ proj_b,
                 float* __restrict__ out) {
  __shared__ short As[2][4096];
  __shared__ short Bs[2][4096];
  const int bid0 = blockIdx.x;                      // 0..2047
  const int swz = ((bid0 & 7) << 8) | (bid0 >> 3);  // bijective: 2048 = 8*256
  const int m0 = (swz >> 2) << 7;
  const int n0 = (swz & 3) << 7;
  const int tid = threadIdx.x;
  const int w = tid >> 6, l = tid & 63, l16 = l & 15, g = l >> 4;
  const int wr = w >> 1, wc = w & 1;
  const int gsw8 = (g ^ ((l16 >> 1) & 3)) << 3;
  const int lrow = l >> 2;
  const int lcol = (((l & 3) ^ ((l >> 3) & 3)) << 3);

  const unsigned short* asrc0 = A + (size_t)(m0 + w * 16 + lrow) * 512 + lcol;
  const unsigned short* asrc1 = asrc0 + (size_t)64 * 512;
  const unsigned short* bsrc0 = BT + (size_t)(n0 + w * 16 + lrow) * 512 + lcol;
  const unsigned short* bsrc1 = bsrc0 + (size_t)64 * 512;

  f32x4v acc[4][4];
#pragma unroll
  for (int mt = 0; mt < 4; ++mt)
#pragma unroll
    for (int nt = 0; nt < 4; ++nt) acc[mt][nt] = (f32x4v)(0.0f);

  auto stage = [&](int t, int bufi) {
    const int k0 = t << 5;
    GLOAD16(asrc0 + k0, As[bufi] + w * 512);
    GLOAD16(asrc1 + k0, As[bufi] + (4 + w) * 512);
    GLOAD16(bsrc0 + k0, Bs[bufi] + w * 512);
    GLOAD16(bsrc1 + k0, Bs[bufi] + (4 + w) * 512);
  };
  stage(0, 0);
#pragma unroll
  for (int t = 0; t < 16; ++t) {
    asm volatile("s_waitcnt vmcnt(0)" ::: "memory");
    __builtin_amdgcn_sched_barrier(0);
    __builtin_amdgcn_s_barrier();
    __builtin_amdgcn_sched_barrier(0);
    if (t < 15) stage(t + 1, (t + 1) & 1);
    const int cur = t & 1;
    short8 af[4], bfr[4];
#pragma unroll
    for (int mt = 0; mt < 4; ++mt)
      af[mt] = *reinterpret_cast<short8*>(&As[cur][(wr * 64 + mt * 16 + l16) * 32 + gsw8]);
#pragma unroll
    for (int nt = 0; nt < 4; ++nt)
      bfr[nt] = *reinterpret_cast<short8*>(&Bs[cur][(wc * 64 + nt * 16 + l16) * 32 + gsw8]);
#pragma unroll
    for (int mt = 0; mt < 4; ++mt)
#pragma unroll
      for (int nt = 0; nt < 4; ++nt)
        acc[mt][nt] = __builtin_amdgcn_mfma_f32_16x16x32_bf16(af[mt], bfr[nt], acc[mt][nt], 0, 0, 0);
  }
#pragma unroll
  for (int nt = 0; nt < 4; ++nt) {
    const int col = n0 + wc * 64 + nt * 16 + l16;
    const float pb = proj_b[col];
#pragma unroll
    for (int mt = 0; mt < 4; ++mt)
#pragma unroll
      for (int j = 0; j < 4; ++j)
        out[(size_t)(m0 + wr * 64 + mt * 16 + g * 4 + j) * 512 + col] = acc[mt][nt][j] + pb;
  }
}

extern "C" void kernel_launch(void* const* d_in, const int* in_sizes, int n_in,
                              void* d_out, int out_size, void* d_ws, size_t ws_size,
                              hipStream_t stream) {
  const float* x      = (const float*)d_in[0];
  const float* temb   = (const float*)d_in[1];
  const float* qkv_w  = (const float*)d_in[2];
  const float* qkv_b  = (const float*)d_in[3];
  const float* temb_w = (const float*)d_in[4];
  const float* temb_b = (const float*)d_in[5];
  const float* rpb    = (const float*)d_in[6];
  const float* proj_w = (const float*)d_in[7];
  const float* proj_b = (const float*)d_in[8];
  float* out = (float*)d_out;

  char* ws = (char*)d_ws;
  float* tm               = (float*)ws;                                  // 1,572,864 B
  unsigned short* xb16    = (unsigned short*)(ws + 1572864);             // 67,108,864 B
  unsigned short* qkv_wT  = (unsigned short*)(ws + 1572864 + 67108864);  // 1,572,864 B
  unsigned short* proj_wT = (unsigned short*)(ws + 1572864 + 67108864 + 1572864);  // 524,288 B
  unsigned short* attn_ws = (unsigned short*)(ws + 1572864 + 67108864 + 1572864 + 524288); // 67,108,864 B

  prep_kernel<<<1472, 512, 0, stream>>>(temb, temb_w, temb_b, qkv_b, tm,
                                        x, (unsigned*)xb16,
                                        qkv_w, qkv_wT, proj_w, proj_wT);
  fused_attn_kernel<<<B_ * H_, 512, 0, stream>>>(xb16, qkv_wT, rpb, tm, attn_ws);
  proj_kernel<<<2048, 256, 0, stream>>>(attn_ws, proj_wT, proj_b, out);
}

// Round 16
// 311.896 us; speedup vs baseline: 1.0669x; 1.0669x over previous
//
#include <hip/hip_runtime.h>
#include <hip/hip_bf16.h>

#define B_ 256
#define N_ 256
#define H_ 16
// softmax scale folded with log2(e); bias folded with log2(e)
#define SCALE2_ 0.25504526484f   // (1/sqrt(32)) * log2(e)
#define LOG2E_ 1.4426950408889634f

typedef __attribute__((ext_vector_type(8))) short short8;
typedef __attribute__((ext_vector_type(4))) float f32x4v;
typedef unsigned int u32;

// async global->LDS, 16B per lane. LDS dest must be wave-uniform base (+lane*16).
#define GLOAD16(gptr, lptr)                                                        \
  __builtin_amdgcn_global_load_lds((const __attribute__((address_space(1))) u32*)(gptr), \
                                   (__attribute__((address_space(3))) u32*)(lptr), 16, 0, 0)

static __device__ __forceinline__ unsigned cvt_pk_bf16(float lo, float hi) {
  unsigned r;
  asm("v_cvt_pk_bf16_f32 %0, %1, %2" : "=v"(r) : "v"(lo), "v"(hi));
  return r;
}

// K0: fused prep — blocks [0,256): temb_mod; [256,1280): cvt_x; [1280,1536): W transposes.
// (r15's temb re-tile regressed +20us: these kernels are latency-regime, not
// traffic-regime — byte-count arguments don't transfer. r14 layout restored.)
__global__ __launch_bounds__(512)
void prep_kernel(const float* __restrict__ temb, const float* __restrict__ temb_w,
                 const float* __restrict__ temb_b, const float* __restrict__ qkv_b,
                 float* __restrict__ tm,
                 const float* __restrict__ x, unsigned* __restrict__ xb16,
                 const float* __restrict__ qkv_w, unsigned short* __restrict__ qkv_wT,
                 const float* __restrict__ proj_w, unsigned short* __restrict__ proj_wT) {
  __shared__ __align__(16) char lbuf[17024];
  const int blk = blockIdx.x;
  const int t = threadIdx.x;

  if (blk < 256) {
    // ---- temb_mod: tm[b][j] = temb[b]@temb_w[:,j] + temb_b[j] + qkv_b[j] ----
    float* ts = (float*)lbuf;
    const int b = blk;
    ts[t] = temb[(size_t)b * 512 + t];
    __syncthreads();
    float a0 = temb_b[t] + qkv_b[t];
    float a1 = temb_b[t + 512] + qkv_b[t + 512];
    float a2 = temb_b[t + 1024] + qkv_b[t + 1024];
#pragma unroll 8
    for (int k = 0; k < 512; ++k) {
      const float tv = ts[k];
      const float* wr = temb_w + (size_t)k * 1536 + t;
      a0 += tv * wr[0];
      a1 += tv * wr[512];
      a2 += tv * wr[1024];
    }
    float* o = tm + (size_t)b * 1536 + t;
    o[0] = a0; o[512] = a1; o[1024] = a2;
  } else if (blk < 1280) {
    // ---- cvt_x: f32 -> bf16, 8 elems/thread/iter ----
    const int n8 = (B_ * N_ * 512) / 8;
    int i = (blk - 256) * 512 + t;
    for (; i < n8; i += 1024 * 512) {
      const float4* p = reinterpret_cast<const float4*>(x + (size_t)i * 8);
      float4 a = p[0], b4 = p[1];
      uint4 vv = make_uint4(cvt_pk_bf16(a.x, a.y), cvt_pk_bf16(a.z, a.w),
                            cvt_pk_bf16(b4.x, b4.y), cvt_pk_bf16(b4.z, b4.w));
      *reinterpret_cast<uint4*>(xb16 + (size_t)i * 4) = vv;
    }
  } else {
    // ---- transpose+convert W [512][ncols] f32 -> WT [ncols][512] bf16 ----
    const float* src; unsigned short* dst; int ncols, k0, n0;
    if (blk < 1472) {
      const int idx = blk - 1280;           // 16 k-blocks x 12 n-blocks
      src = qkv_w; dst = qkv_wT; ncols = 1536;
      k0 = (idx / 12) << 5; n0 = (idx % 12) << 7;
    } else {
      const int idx = blk - 1472;           // 16 x 4
      src = proj_w; dst = proj_wT; ncols = 512;
      k0 = (idx >> 2) << 5; n0 = (idx & 3) << 7;
    }
    float (*tile)[133] = (float (*)[133])lbuf;   // 32 x 128 tile, pad 133
    {
      const int kk = t >> 4, c0 = (t & 15) << 3;
      const float* s = src + (size_t)(k0 + kk) * ncols + n0 + c0;
      float4 v0 = *reinterpret_cast<const float4*>(s);
      float4 v1 = *reinterpret_cast<const float4*>(s + 4);
      tile[kk][c0 + 0] = v0.x; tile[kk][c0 + 1] = v0.y; tile[kk][c0 + 2] = v0.z; tile[kk][c0 + 3] = v0.w;
      tile[kk][c0 + 4] = v1.x; tile[kk][c0 + 5] = v1.y; tile[kk][c0 + 6] = v1.z; tile[kk][c0 + 7] = v1.w;
    }
    __syncthreads();
    {
      const int nn = t >> 2, ck = (t & 3) << 3;
      uint4 vv = make_uint4(cvt_pk_bf16(tile[ck + 0][nn], tile[ck + 1][nn]),
                            cvt_pk_bf16(tile[ck + 2][nn], tile[ck + 3][nn]),
                            cvt_pk_bf16(tile[ck + 4][nn], tile[ck + 5][nn]),
                            cvt_pk_bf16(tile[ck + 6][nn], tile[ck + 7][nn]));
      *reinterpret_cast<uint4*>(dst + (size_t)(n0 + nn) * 512 + k0 + ck) = vv;
    }
  }
}

// K1: fused qkv-GEMM + flash attention per (b,h). 512 thr, 8 waves.
// Phase A: 3-buffer gload_lds staging with counted-vmcnt raw barriers (r10/r12
// version, measured 196us). r11 (f32 reg-stage x) and r13 (W direct-to-reg,
// barrier-free) both regressed: any operand consumed same-iteration must come
// from LDS staged >=1 iter ahead — scattered global->reg loads with zero
// lookahead serialize L2 latency into every k-step.
// Flash: NO online max, bias as MFMA C-input, lsum via ones-B MFMA, rcp.
// __launch_bounds__(512,4): 128-reg budget; waves=6 spilled (r3/r4 lesson).
__global__ __launch_bounds__(512, 4)
void fused_attn_kernel(const unsigned short* __restrict__ xb16,   // [65536][512]
                       const unsigned short* __restrict__ wT,     // [1536][512]
                       const float* __restrict__ rpb,
                       const float* __restrict__ tm,
                       unsigned short* __restrict__ attn_out) {
  // bytes: x-stage x3 [0,49152) | W-stage x3 [49152,67584)
  // after phase A: qs [0,16384), ks [16384,32768), vTs [32768,49152), bias [49152,53000)
  __shared__ __align__(16) char smem[67584];
  short* xs     = (short*)smem;             // x buffers / qs
  short* ksp    = (short*)(smem + 16384);   // ks (persistent)
  short* vTs    = (short*)(smem + 32768);   // vTs (persistent)
  short* wstage = (short*)(smem + 49152);   // W buffers x3
  float* biasT  = (float*)(smem + 49152);   // bias (after staging dead)

  // bijective XCD remap: blockIdx%8 ~ XCD; give each XCD 32 consecutive b
  const int u = blockIdx.x;
  const int bh = ((u & 7) << 9) | (u >> 3);
  const int b = bh >> 4, h = bh & 15;
  const int tid = threadIdx.x;
  const int w = tid >> 6, l = tid & 63;
  const int l16 = l & 15, g = l >> 4;
  const int gsw8 = (g ^ ((l16 >> 1) & 3)) << 3;          // swizzled frag offset (shorts)
  const int lrow = l >> 2;
  const int lcol = (((l & 3) ^ ((l >> 3) & 3)) << 3);    // swizzled source col

  const unsigned short* xsrc0 = xb16 + (size_t)(b * 256 + w * 16 + lrow) * 512 + lcol;
  const unsigned short* xsrc1 = xsrc0 + (size_t)128 * 512;
  const int row96 = w * 16 + lrow;
  const unsigned short* wsrc = wT + (size_t)((row96 >> 5) * 512 + h * 32 + (row96 & 31)) * 512 + lcol;

  f32x4v acc[2][6];
#pragma unroll
  for (int mt = 0; mt < 2; ++mt)
#pragma unroll
    for (int nt = 0; nt < 6; ++nt) acc[mt][nt] = (f32x4v)(0.0f);

  // ---- Phase A (3-buf, counted-vmcnt single barrier per k-tile) ----
  auto stage = [&](int t, int bufi) {
    const int k0 = t << 5;
    GLOAD16(xsrc0 + k0, xs + bufi * 8192 + w * 512);
    GLOAD16(xsrc1 + k0, xs + bufi * 8192 + (8 + w) * 512);
    if (w < 6) GLOAD16(wsrc + k0, wstage + bufi * 3072 + w * 512);
  };
  stage(0, 0);
#pragma unroll
  for (int t = 0; t < 16; ++t) {
    const int buf = t % 3;
    if (t < 15) {
      stage(t + 1, (t + 1) % 3);
      if (w < 6) asm volatile("s_waitcnt vmcnt(3)" ::: "memory");
      else       asm volatile("s_waitcnt vmcnt(2)" ::: "memory");
    } else {
      asm volatile("s_waitcnt vmcnt(0)" ::: "memory");
    }
    __builtin_amdgcn_sched_barrier(0);
    __builtin_amdgcn_s_barrier();
    __builtin_amdgcn_sched_barrier(0);
    short* xb = xs + buf * 8192;
    short* wb = wstage + buf * 3072;
    short8 af[2], bfr[6];
#pragma unroll
    for (int mt = 0; mt < 2; ++mt)
      af[mt] = *reinterpret_cast<short8*>(&xb[(w * 32 + mt * 16 + l16) * 32 + gsw8]);
#pragma unroll
    for (int nt = 0; nt < 6; ++nt)
      bfr[nt] = *reinterpret_cast<short8*>(&wb[(nt * 16 + l16) * 32 + gsw8]);
#pragma unroll
    for (int mt = 0; mt < 2; ++mt)
#pragma unroll
      for (int nt = 0; nt < 6; ++nt)
        acc[mt][nt] = __builtin_amdgcn_mfma_f32_16x16x32_bf16(af[mt], bfr[nt], acc[mt][nt], 0, 0, 0);
  }
  __syncthreads();   // all reads done before epilogue overwrites staging regions

  // ---- epilogue A: +tm bias; q (log2-scaled) -> xs, k -> ksp, v -> vTs ----
  const float* tmb = tm + (size_t)b * 1536 + h * 32;
#pragma unroll
  for (int nt = 0; nt < 6; ++nt) {
    const int prt = nt >> 1;
    const int d = ((nt & 1) << 4) + l16;
    const float tmv = tmb[(prt << 9) + d];
#pragma unroll
    for (int mt = 0; mt < 2; ++mt) {
      const int r0 = w * 32 + mt * 16 + g * 4;
      float v0 = acc[mt][nt][0] + tmv, v1 = acc[mt][nt][1] + tmv;
      float v2 = acc[mt][nt][2] + tmv, v3 = acc[mt][nt][3] + tmv;
      if (prt == 0) { v0 *= SCALE2_; v1 *= SCALE2_; v2 *= SCALE2_; v3 *= SCALE2_; }
      const u32 p01 = cvt_pk_bf16(v0, v1);
      const u32 p23 = cvt_pk_bf16(v2, v3);
      if (prt != 2) {
        short* dst = (prt == 0) ? xs : ksp;
        const int unit01 = ((d >> 3) ^ ((r0 >> 1) & 3)) << 3;
        const int base = r0 * 32 + unit01 + (d & 7);
        // rows r0,r0+1 share unit; r0+2,r0+3 have unit^1 (r0 ≡ 0 mod 4)
        dst[base]            = (short)p01;
        dst[base + 32]       = (short)(p01 >> 16);
        dst[(base + 64) ^ 8] = (short)p23;
        dst[(base + 96) ^ 8] = (short)(p23 >> 16);
      } else {
#pragma unroll
        for (int j = 0; j < 4; ++j) {
          const int key = r0 + j;
          const int vcol = ((key >> 5) << 5) | (((key & 15) << 1) | ((key >> 4) & 1));
          const int unit = ((vcol >> 3) ^ (d & 7));
          const u32 pk = (j < 2) ? p01 : p23;
          vTs[d * 256 + (unit << 3) + (vcol & 7)] = (short)(pk >> ((j & 1) << 4));
        }
      }
    }
  }
  for (int e = tid; e < 961; e += 512) biasT[e] = rpb[e * 16 + h] * LOG2E_;
  __syncthreads();

  // ---- flash attention: S^T = mfma(K, Q, C=bias); P in registers; no max ----
  short8 bq[2];
#pragma unroll
  for (int mt = 0; mt < 2; ++mt)
    bq[mt] = *reinterpret_cast<short8*>(&xs[(w * 32 + mt * 16 + l16) * 32 + gsw8]);

  const int bcol = l16 - (g << 2) + 15;    // [0,30]
  const int brow0 = w * 2 + 15;

  f32x4v bp_prev;
#pragma unroll
  for (int j = 0; j < 4; ++j) bp_prev[j] = biasT[(brow0 + 1) * 31 + bcol - j];

  // all-ones bf16 B-fragment for the lsum MFMA
  short8 ones8;
#pragma unroll
  for (int j = 0; j < 8; ++j) ones8[j] = (short)0x3F80;

  f32x4v oacc[2][2];
  f32x4v oaccL[2];
#pragma unroll
  for (int mt = 0; mt < 2; ++mt) {
    oacc[mt][0] = (f32x4v)(0.0f);
    oacc[mt][1] = (f32x4v)(0.0f);
    oaccL[mt] = (f32x4v)(0.0f);
  }

#pragma unroll
  for (int kc = 0; kc < 8; ++kc) {
    const int kt0 = kc * 2, kt1 = kc * 2 + 1;
    short8 kf0 = *reinterpret_cast<short8*>(&ksp[(kt0 * 16 + l16) * 32 + gsw8]);
    short8 kf1 = *reinterpret_cast<short8*>(&ksp[(kt1 * 16 + l16) * 32 + gsw8]);
    f32x4v cA, cB;
    const float* brA = biasT + (brow0 - kt0) * 31 + bcol;
    const float* brB = biasT + (brow0 - kt1) * 31 + bcol;
#pragma unroll
    for (int j = 0; j < 4; ++j) { cA[j] = brA[-j]; cB[j] = brB[-j]; }
    f32x4v s00, s01, s10, s11;   // s[ct][mt]
    __builtin_amdgcn_s_setprio(1);
    s00 = __builtin_amdgcn_mfma_f32_16x16x32_bf16(kf0, bq[0], cA, 0, 0, 0);
    s01 = __builtin_amdgcn_mfma_f32_16x16x32_bf16(kf0, bq[1], bp_prev, 0, 0, 0);
    s10 = __builtin_amdgcn_mfma_f32_16x16x32_bf16(kf1, bq[0], cB, 0, 0, 0);
    s11 = __builtin_amdgcn_mfma_f32_16x16x32_bf16(kf1, bq[1], cA, 0, 0, 0);
    __builtin_amdgcn_s_setprio(0);
    bp_prev = cB;

    short8 pa0, pa1;
    {
      union { u32 u[4]; short8 s8; } pk0, pk1;
#pragma unroll
      for (int j = 0; j < 4; ++j) {
        pk0.u[j] = cvt_pk_bf16(exp2f(s00[j]), exp2f(s10[j]));
        pk1.u[j] = cvt_pk_bf16(exp2f(s01[j]), exp2f(s11[j]));
      }
      pa0 = pk0.s8; pa1 = pk1.s8;
    }
    short8 bv0 = *reinterpret_cast<short8*>(
        &vTs[(l16) * 256 + ((((kc * 4 + g) ^ (l16 & 7)) << 3))]);
    short8 bv1 = *reinterpret_cast<short8*>(
        &vTs[(16 + l16) * 256 + ((((kc * 4 + g) ^ (l16 & 7)) << 3))]);
    __builtin_amdgcn_s_setprio(1);
    oacc[0][0] = __builtin_amdgcn_mfma_f32_16x16x32_bf16(pa0, bv0, oacc[0][0], 0, 0, 0);
    oacc[0][1] = __builtin_amdgcn_mfma_f32_16x16x32_bf16(pa0, bv1, oacc[0][1], 0, 0, 0);
    oacc[1][0] = __builtin_amdgcn_mfma_f32_16x16x32_bf16(pa1, bv0, oacc[1][0], 0, 0, 0);
    oacc[1][1] = __builtin_amdgcn_mfma_f32_16x16x32_bf16(pa1, bv1, oacc[1][1], 0, 0, 0);
    oaccL[0]   = __builtin_amdgcn_mfma_f32_16x16x32_bf16(pa0, ones8, oaccL[0], 0, 0, 0);
    oaccL[1]   = __builtin_amdgcn_mfma_f32_16x16x32_bf16(pa1, ones8, oaccL[1], 0, 0, 0);
    __builtin_amdgcn_s_setprio(0);
  }

  // ---- normalize (lsum already in-lane via ones-MFMA), bounce O, store ----
  float i0[4], i1[4];
#pragma unroll
  for (int j = 0; j < 4; ++j) {
    i0[j] = __builtin_amdgcn_rcpf(oaccL[0][j]);
    i1[j] = __builtin_amdgcn_rcpf(oaccL[1][j]);
  }
  short* ob = xs + w * 1024;   // own wave's 32x32 region, dead after bq load
  const int u0 = (((l16 >> 3) ^ g) << 3) + (l16 & 7);
  const int u1 = ((((l16 >> 3) | 2) ^ g) << 3) + (l16 & 7);
  {
    const u32 a01 = cvt_pk_bf16(oacc[0][0][0] * i0[0], oacc[0][0][1] * i0[1]);
    const u32 a23 = cvt_pk_bf16(oacc[0][0][2] * i0[2], oacc[0][0][3] * i0[3]);
    const u32 b01 = cvt_pk_bf16(oacc[0][1][0] * i0[0], oacc[0][1][1] * i0[1]);
    const u32 b23 = cvt_pk_bf16(oacc[0][1][2] * i0[2], oacc[0][1][3] * i0[3]);
    const u32 c01 = cvt_pk_bf16(oacc[1][0][0] * i1[0], oacc[1][0][1] * i1[1]);
    const u32 c23 = cvt_pk_bf16(oacc[1][0][2] * i1[2], oacc[1][0][3] * i1[3]);
    const u32 d01 = cvt_pk_bf16(oacc[1][1][0] * i1[0], oacc[1][1][1] * i1[1]);
    const u32 d23 = cvt_pk_bf16(oacc[1][1][2] * i1[2], oacc[1][1][3] * i1[3]);
    const int r0 = (g << 2) * 32;
    ob[r0 + u0]       = (short)a01;  ob[r0 + 32 + u0]  = (short)(a01 >> 16);
    ob[r0 + 64 + u0]  = (short)a23;  ob[r0 + 96 + u0]  = (short)(a23 >> 16);
    ob[r0 + u1]       = (short)b01;  ob[r0 + 32 + u1]  = (short)(b01 >> 16);
    ob[r0 + 64 + u1]  = (short)b23;  ob[r0 + 96 + u1]  = (short)(b23 >> 16);
    const int r1 = r0 + 512;
    ob[r1 + u0]       = (short)c01;  ob[r1 + 32 + u0]  = (short)(c01 >> 16);
    ob[r1 + 64 + u0]  = (short)c23;  ob[r1 + 96 + u0]  = (short)(c23 >> 16);
    ob[r1 + u1]       = (short)d01;  ob[r1 + 32 + u1]  = (short)(d01 >> 16);
    ob[r1 + 64 + u1]  = (short)d23;  ob[r1 + 96 + u1]  = (short)(d23 >> 16);
  }
  // own-wave region: no barrier needed (compiler orders ds_write->ds_read)
  unsigned short* aw = attn_out + (size_t)(b * 256 + w * 32) * 512 + h * 32;
#pragma unroll
  for (int i = 0; i < 2; ++i) {
    const int r = i * 16 + (l >> 2);
    const int cu = l & 3;
    const int su = cu ^ ((r >> 2) & 3);
    short8 vv = *reinterpret_cast<short8*>(&ob[r * 32 + (su << 3)]);
    *reinterpret_cast<short8*>(aw + (size_t)r * 512 + (cu << 3)) = vv;
  }
}

// K2: out = attn @ proj_wT^T + proj_b  (2-buf, issue-after-barrier counted scheme)
__global__ __launch_bounds__(256)
void proj_kernel(const unsigned short* __restrict__ A,    // [65536][512] bf16
                 const unsigned short* __restrict__ BT,   // [512][512] bf16
                 const float* __restrict__ proj_b,
                 float* __restrict__ out) {
  __shared__ short As[2][4096];
  __shared__ short Bs[2][4096];
  const int bid0 = blockIdx.x;                      // 0..2047
  const int swz = ((bid0 & 7) << 8) | (bid0 >> 3);  // bijective: 2048 = 8*256
  const int m0 = (swz >> 2) << 7;
  const int n0 = (swz & 3) << 7;
  const int tid = threadIdx.x;
  const int w = tid >> 6, l = tid & 63, l16 = l & 15, g = l >> 4;
  const int wr = w >> 1, wc = w & 1;
  const int gsw8 = (g ^ ((l16 >> 1) & 3)) << 3;
  const int lrow = l >> 2;
  const int lcol = (((l & 3) ^ ((l >> 3) & 3)) << 3);

  const unsigned short* asrc0 = A + (size_t)(m0 + w * 16 + lrow) * 512 + lcol;
  const unsigned short* asrc1 = asrc0 + (size_t)64 * 512;
  const unsigned short* bsrc0 = BT + (size_t)(n0 + w * 16 + lrow) * 512 + lcol;
  const unsigned short* bsrc1 = bsrc0 + (size_t)64 * 512;

  f32x4v acc[4][4];
#pragma unroll
  for (int mt = 0; mt < 4; ++mt)
#pragma unroll
    for (int nt = 0; nt < 4; ++nt) acc[mt][nt] = (f32x4v)(0.0f);

  auto stage = [&](int t, int bufi) {
    const int k0 = t << 5;
    GLOAD16(asrc0 + k0, As[bufi] + w * 512);
    GLOAD16(asrc1 + k0, As[bufi] + (4 + w) * 512);
    GLOAD16(bsrc0 + k0, Bs[bufi] + w * 512);
    GLOAD16(bsrc1 + k0, Bs[bufi] + (4 + w) * 512);
  };
  stage(0, 0);
#pragma unroll
  for (int t = 0; t < 16; ++t) {
    asm volatile("s_waitcnt vmcnt(0)" ::: "memory");
    __builtin_amdgcn_sched_barrier(0);
    __builtin_amdgcn_s_barrier();
    __builtin_amdgcn_sched_barrier(0);
    if (t < 15) stage(t + 1, (t + 1) & 1);
    const int cur = t & 1;
    short8 af[4], bfr[4];
#pragma unroll
    for (int mt = 0; mt < 4; ++mt)
      af[mt] = *reinterpret_cast<short8*>(&As[cur][(wr * 64 + mt * 16 + l16) * 32 + gsw8]);
#pragma unroll
    for (int nt = 0; nt < 4; ++nt)
      bfr[nt] = *reinterpret_cast<short8*>(&Bs[cur][(wc * 64 + nt * 16 + l16) * 32 + gsw8]);
#pragma unroll
    for (int mt = 0; mt < 4; ++mt)
#pragma unroll
      for (int nt = 0; nt < 4; ++nt)
        acc[mt][nt] = __builtin_amdgcn_mfma_f32_16x16x32_bf16(af[mt], bfr[nt], acc[mt][nt], 0, 0, 0);
  }
#pragma unroll
  for (int nt = 0; nt < 4; ++nt) {
    const int col = n0 + wc * 64 + nt * 16 + l16;
    const float pb = proj_b[col];
#pragma unroll
    for (int mt = 0; mt < 4; ++mt)
#pragma unroll
      for (int j = 0; j < 4; ++j)
        out[(size_t)(m0 + wr * 64 + mt * 16 + g * 4 + j) * 512 + col] = acc[mt][nt][j] + pb;
  }
}

extern "C" void kernel_launch(void* const* d_in, const int* in_sizes, int n_in,
                              void* d_out, int out_size, void* d_ws, size_t ws_size,
                              hipStream_t stream) {
  const float* x      = (const float*)d_in[0];
  const float* temb   = (const float*)d_in[1];
  const float* qkv_w  = (const float*)d_in[2];
  const float* qkv_b  = (const float*)d_in[3];
  const float* temb_w = (const float*)d_in[4];
  const float* temb_b = (const float*)d_in[5];
  const float* rpb    = (const float*)d_in[6];
  const float* proj_w = (const float*)d_in[7];
  const float* proj_b = (const float*)d_in[8];
  float* out = (float*)d_out;

  char* ws = (char*)d_ws;
  float* tm               = (float*)ws;                                  // 1,572,864 B
  unsigned short* xb16    = (unsigned short*)(ws + 1572864);             // 67,108,864 B
  unsigned short* qkv_wT  = (unsigned short*)(ws + 1572864 + 67108864);  // 1,572,864 B
  unsigned short* proj_wT = (unsigned short*)(ws + 1572864 + 67108864 + 1572864);  // 524,288 B
  unsigned short* attn_ws = (unsigned short*)(ws + 1572864 + 67108864 + 1572864 + 524288); // 67,108,864 B

  prep_kernel<<<1536, 512, 0, stream>>>(temb, temb_w, temb_b, qkv_b, tm,
                                        x, (unsigned*)xb16,
                                        qkv_w, qkv_wT, proj_w, proj_wT);
  fused_attn_kernel<<<B_ * H_, 512, 0, stream>>>(xb16, qkv_wT, rpb, tm, attn_ws);
  proj_kernel<<<2048, 256, 0, stream>>>(attn_ws, proj_wT, proj_b, out);
}

// Round 17
// 309.748 us; speedup vs baseline: 1.0743x; 1.0069x over previous
//
#include <hip/hip_runtime.h>
#include <hip/hip_bf16.h>

#define B_ 256
#define N_ 256
#define H_ 16
// softmax scale folded with log2(e); bias folded with log2(e)
#define SCALE2_ 0.25504526484f   // (1/sqrt(32)) * log2(e)
#define LOG2E_ 1.4426950408889634f

typedef __attribute__((ext_vector_type(8))) short short8;
typedef __attribute__((ext_vector_type(4))) float f32x4v;
typedef unsigned int u32;

// async global->LDS, 16B per lane. LDS dest must be wave-uniform base (+lane*16).
#define GLOAD16(gptr, lptr)                                                        \
  __builtin_amdgcn_global_load_lds((const __attribute__((address_space(1))) u32*)(gptr), \
                                   (__attribute__((address_space(3))) u32*)(lptr), 16, 0, 0)

static __device__ __forceinline__ unsigned cvt_pk_bf16(float lo, float hi) {
  unsigned r;
  asm("v_cvt_pk_bf16_f32 %0, %1, %2" : "=v"(r) : "v"(lo), "v"(hi));
  return r;
}

// K0: fused prep — blocks [0,256): temb_mod; [256,1280): cvt_x; [1280,1536): W transposes.
__global__ __launch_bounds__(512)
void prep_kernel(const float* __restrict__ temb, const float* __restrict__ temb_w,
                 const float* __restrict__ temb_b, const float* __restrict__ qkv_b,
                 float* __restrict__ tm,
                 const float* __restrict__ x, unsigned* __restrict__ xb16,
                 const float* __restrict__ qkv_w, unsigned short* __restrict__ qkv_wT,
                 const float* __restrict__ proj_w, unsigned short* __restrict__ proj_wT) {
  __shared__ __align__(16) char lbuf[17024];
  const int blk = blockIdx.x;
  const int t = threadIdx.x;

  if (blk < 256) {
    // ---- temb_mod: tm[b][j] = temb[b]@temb_w[:,j] + temb_b[j] + qkv_b[j] ----
    float* ts = (float*)lbuf;
    const int b = blk;
    ts[t] = temb[(size_t)b * 512 + t];
    __syncthreads();
    float a0 = temb_b[t] + qkv_b[t];
    float a1 = temb_b[t + 512] + qkv_b[t + 512];
    float a2 = temb_b[t + 1024] + qkv_b[t + 1024];
#pragma unroll 8
    for (int k = 0; k < 512; ++k) {
      const float tv = ts[k];
      const float* wr = temb_w + (size_t)k * 1536 + t;
      a0 += tv * wr[0];
      a1 += tv * wr[512];
      a2 += tv * wr[1024];
    }
    float* o = tm + (size_t)b * 1536 + t;
    o[0] = a0; o[512] = a1; o[1024] = a2;
  } else if (blk < 1280) {
    // ---- cvt_x: f32 -> bf16, 8 elems/thread/iter ----
    const int n8 = (B_ * N_ * 512) / 8;
    int i = (blk - 256) * 512 + t;
    for (; i < n8; i += 1024 * 512) {
      const float4* p = reinterpret_cast<const float4*>(x + (size_t)i * 8);
      float4 a = p[0], b4 = p[1];
      uint4 vv = make_uint4(cvt_pk_bf16(a.x, a.y), cvt_pk_bf16(a.z, a.w),
                            cvt_pk_bf16(b4.x, b4.y), cvt_pk_bf16(b4.z, b4.w));
      *reinterpret_cast<uint4*>(xb16 + (size_t)i * 4) = vv;
    }
  } else {
    // ---- transpose+convert W [512][ncols] f32 -> WT [ncols][512] bf16 ----
    const float* src; unsigned short* dst; int ncols, k0, n0;
    if (blk < 1472) {
      const int idx = blk - 1280;           // 16 k-blocks x 12 n-blocks
      src = qkv_w; dst = qkv_wT; ncols = 1536;
      k0 = (idx / 12) << 5; n0 = (idx % 12) << 7;
    } else {
      const int idx = blk - 1472;           // 16 x 4
      src = proj_w; dst = proj_wT; ncols = 512;
      k0 = (idx >> 2) << 5; n0 = (idx & 3) << 7;
    }
    float (*tile)[133] = (float (*)[133])lbuf;   // 32 x 128 tile, pad 133
    {
      const int kk = t >> 4, c0 = (t & 15) << 3;
      const float* s = src + (size_t)(k0 + kk) * ncols + n0 + c0;
      float4 v0 = *reinterpret_cast<const float4*>(s);
      float4 v1 = *reinterpret_cast<const float4*>(s + 4);
      tile[kk][c0 + 0] = v0.x; tile[kk][c0 + 1] = v0.y; tile[kk][c0 + 2] = v0.z; tile[kk][c0 + 3] = v0.w;
      tile[kk][c0 + 4] = v1.x; tile[kk][c0 + 5] = v1.y; tile[kk][c0 + 6] = v1.z; tile[kk][c0 + 7] = v1.w;
    }
    __syncthreads();
    {
      const int nn = t >> 2, ck = (t & 3) << 3;
      uint4 vv = make_uint4(cvt_pk_bf16(tile[ck + 0][nn], tile[ck + 1][nn]),
                            cvt_pk_bf16(tile[ck + 2][nn], tile[ck + 3][nn]),
                            cvt_pk_bf16(tile[ck + 4][nn], tile[ck + 5][nn]),
                            cvt_pk_bf16(tile[ck + 6][nn], tile[ck + 7][nn]));
      *reinterpret_cast<uint4*>(dst + (size_t)(n0 + nn) * 512 + k0 + ck) = vv;
    }
  }
}

// K1: fused qkv-GEMM + flash attention per (b,h). 512 thr, 8 waves.
// Phase A: 3-buffer gload_lds staging with counted-vmcnt raw barriers.
// Bias (rpb) now staged into its OWN LDS region at kernel start: its loads are
// issued before the K-loop and retire under the stage(0) drain (previously a
// cold uncoalesced load serialized between epilogue and flash). The extra
// in-flight ops are OLDER than every counted vmcnt window, so vmcnt(3)/(2)
// still guarantees stage(t) retirement (strictly conservative at t=0).
// Flash: NO online max, bias as MFMA C-input, lsum via ones-B MFMA, rcp.
// __launch_bounds__(512,4): 128-reg budget; waves=6 spilled (r3/r4 lesson).
__global__ __launch_bounds__(512, 4)
void fused_attn_kernel(const unsigned short* __restrict__ xb16,   // [65536][512]
                       const unsigned short* __restrict__ wT,     // [1536][512]
                       const float* __restrict__ rpb,
                       const float* __restrict__ tm,
                       unsigned short* __restrict__ attn_out) {
  // bytes: x-stage x3 [0,49152) | W-stage x3 [49152,67584) | biasT [67584,71428)
  // after phase A: qs [0,16384), ks [16384,32768), vTs [32768,49152)
  __shared__ __align__(16) char smem[71440];
  short* xs     = (short*)smem;             // x buffers / qs
  short* ksp    = (short*)(smem + 16384);   // ks (persistent)
  short* vTs    = (short*)(smem + 32768);   // vTs (persistent)
  short* wstage = (short*)(smem + 49152);   // W buffers x3
  float* biasT  = (float*)(smem + 67584);   // bias (own region, loaded early)

  // bijective XCD remap: blockIdx%8 ~ XCD; give each XCD 32 consecutive b
  const int u = blockIdx.x;
  const int bh = ((u & 7) << 9) | (u >> 3);
  const int b = bh >> 4, h = bh & 15;
  const int tid = threadIdx.x;
  const int w = tid >> 6, l = tid & 63;
  const int l16 = l & 15, g = l >> 4;
  const int gsw8 = (g ^ ((l16 >> 1) & 3)) << 3;          // swizzled frag offset (shorts)
  const int lrow = l >> 2;
  const int lcol = (((l & 3) ^ ((l >> 3) & 3)) << 3);    // swizzled source col

  const unsigned short* xsrc0 = xb16 + (size_t)(b * 256 + w * 16 + lrow) * 512 + lcol;
  const unsigned short* xsrc1 = xsrc0 + (size_t)128 * 512;
  const int row96 = w * 16 + lrow;
  const unsigned short* wsrc = wT + (size_t)((row96 >> 5) * 512 + h * 32 + (row96 & 31)) * 512 + lcol;

  f32x4v acc[2][6];
#pragma unroll
  for (int mt = 0; mt < 2; ++mt)
#pragma unroll
    for (int nt = 0; nt < 6; ++nt) acc[mt][nt] = (f32x4v)(0.0f);

  // ---- Phase A (3-buf, counted-vmcnt single barrier per k-tile) ----
  auto stage = [&](int t, int bufi) {
    const int k0 = t << 5;
    GLOAD16(xsrc0 + k0, xs + bufi * 8192 + w * 512);
    GLOAD16(xsrc1 + k0, xs + bufi * 8192 + (8 + w) * 512);
    if (w < 6) GLOAD16(wsrc + k0, wstage + bufi * 3072 + w * 512);
  };
  stage(0, 0);
  // early bias staging: loads retire under the stage(0) drain at t=0
  for (int e = tid; e < 961; e += 512) biasT[e] = rpb[e * 16 + h] * LOG2E_;
#pragma unroll
  for (int t = 0; t < 16; ++t) {
    const int buf = t % 3;
    if (t < 15) {
      stage(t + 1, (t + 1) % 3);
      if (w < 6) asm volatile("s_waitcnt vmcnt(3)" ::: "memory");
      else       asm volatile("s_waitcnt vmcnt(2)" ::: "memory");
    } else {
      asm volatile("s_waitcnt vmcnt(0)" ::: "memory");
    }
    __builtin_amdgcn_sched_barrier(0);
    __builtin_amdgcn_s_barrier();
    __builtin_amdgcn_sched_barrier(0);
    short* xb = xs + buf * 8192;
    short* wb = wstage + buf * 3072;
    short8 af[2], bfr[6];
#pragma unroll
    for (int mt = 0; mt < 2; ++mt)
      af[mt] = *reinterpret_cast<short8*>(&xb[(w * 32 + mt * 16 + l16) * 32 + gsw8]);
#pragma unroll
    for (int nt = 0; nt < 6; ++nt)
      bfr[nt] = *reinterpret_cast<short8*>(&wb[(nt * 16 + l16) * 32 + gsw8]);
#pragma unroll
    for (int mt = 0; mt < 2; ++mt)
#pragma unroll
      for (int nt = 0; nt < 6; ++nt)
        acc[mt][nt] = __builtin_amdgcn_mfma_f32_16x16x32_bf16(af[mt], bfr[nt], acc[mt][nt], 0, 0, 0);
  }
  __syncthreads();   // all reads done before epilogue overwrites staging regions

  // ---- epilogue A: +tm bias; q (log2-scaled) -> xs, k -> ksp, v -> vTs ----
  const float* tmb = tm + (size_t)b * 1536 + h * 32;
#pragma unroll
  for (int nt = 0; nt < 6; ++nt) {
    const int prt = nt >> 1;
    const int d = ((nt & 1) << 4) + l16;
    const float tmv = tmb[(prt << 9) + d];
#pragma unroll
    for (int mt = 0; mt < 2; ++mt) {
      const int r0 = w * 32 + mt * 16 + g * 4;
      float v0 = acc[mt][nt][0] + tmv, v1 = acc[mt][nt][1] + tmv;
      float v2 = acc[mt][nt][2] + tmv, v3 = acc[mt][nt][3] + tmv;
      if (prt == 0) { v0 *= SCALE2_; v1 *= SCALE2_; v2 *= SCALE2_; v3 *= SCALE2_; }
      const u32 p01 = cvt_pk_bf16(v0, v1);
      const u32 p23 = cvt_pk_bf16(v2, v3);
      if (prt != 2) {
        short* dst = (prt == 0) ? xs : ksp;
        const int unit01 = ((d >> 3) ^ ((r0 >> 1) & 3)) << 3;
        const int base = r0 * 32 + unit01 + (d & 7);
        // rows r0,r0+1 share unit; r0+2,r0+3 have unit^1 (r0 ≡ 0 mod 4)
        dst[base]            = (short)p01;
        dst[base + 32]       = (short)(p01 >> 16);
        dst[(base + 64) ^ 8] = (short)p23;
        dst[(base + 96) ^ 8] = (short)(p23 >> 16);
      } else {
#pragma unroll
        for (int j = 0; j < 4; ++j) {
          const int key = r0 + j;
          const int vcol = ((key >> 5) << 5) | (((key & 15) << 1) | ((key >> 4) & 1));
          const int unit = ((vcol >> 3) ^ (d & 7));
          const u32 pk = (j < 2) ? p01 : p23;
          vTs[d * 256 + (unit << 3) + (vcol & 7)] = (short)(pk >> ((j & 1) << 4));
        }
      }
    }
  }
  __syncthreads();

  // ---- flash attention: S^T = mfma(K, Q, C=bias); P in registers; no max ----
  short8 bq[2];
#pragma unroll
  for (int mt = 0; mt < 2; ++mt)
    bq[mt] = *reinterpret_cast<short8*>(&xs[(w * 32 + mt * 16 + l16) * 32 + gsw8]);

  const int bcol = l16 - (g << 2) + 15;    // [0,30]
  const int brow0 = w * 2 + 15;

  f32x4v bp_prev;
#pragma unroll
  for (int j = 0; j < 4; ++j) bp_prev[j] = biasT[(brow0 + 1) * 31 + bcol - j];

  // all-ones bf16 B-fragment for the lsum MFMA
  short8 ones8;
#pragma unroll
  for (int j = 0; j < 8; ++j) ones8[j] = (short)0x3F80;

  f32x4v oacc[2][2];
  f32x4v oaccL[2];
#pragma unroll
  for (int mt = 0; mt < 2; ++mt) {
    oacc[mt][0] = (f32x4v)(0.0f);
    oacc[mt][1] = (f32x4v)(0.0f);
    oaccL[mt] = (f32x4v)(0.0f);
  }

#pragma unroll
  for (int kc = 0; kc < 8; ++kc) {
    const int kt0 = kc * 2, kt1 = kc * 2 + 1;
    short8 kf0 = *reinterpret_cast<short8*>(&ksp[(kt0 * 16 + l16) * 32 + gsw8]);
    short8 kf1 = *reinterpret_cast<short8*>(&ksp[(kt1 * 16 + l16) * 32 + gsw8]);
    f32x4v cA, cB;
    const float* brA = biasT + (brow0 - kt0) * 31 + bcol;
    const float* brB = biasT + (brow0 - kt1) * 31 + bcol;
#pragma unroll
    for (int j = 0; j < 4; ++j) { cA[j] = brA[-j]; cB[j] = brB[-j]; }
    f32x4v s00, s01, s10, s11;   // s[ct][mt]
    __builtin_amdgcn_s_setprio(1);
    s00 = __builtin_amdgcn_mfma_f32_16x16x32_bf16(kf0, bq[0], cA, 0, 0, 0);
    s01 = __builtin_amdgcn_mfma_f32_16x16x32_bf16(kf0, bq[1], bp_prev, 0, 0, 0);
    s10 = __builtin_amdgcn_mfma_f32_16x16x32_bf16(kf1, bq[0], cB, 0, 0, 0);
    s11 = __builtin_amdgcn_mfma_f32_16x16x32_bf16(kf1, bq[1], cA, 0, 0, 0);
    __builtin_amdgcn_s_setprio(0);
    bp_prev = cB;

    short8 pa0, pa1;
    {
      union { u32 u[4]; short8 s8; } pk0, pk1;
#pragma unroll
      for (int j = 0; j < 4; ++j) {
        pk0.u[j] = cvt_pk_bf16(exp2f(s00[j]), exp2f(s10[j]));
        pk1.u[j] = cvt_pk_bf16(exp2f(s01[j]), exp2f(s11[j]));
      }
      pa0 = pk0.s8; pa1 = pk1.s8;
    }
    short8 bv0 = *reinterpret_cast<short8*>(
        &vTs[(l16) * 256 + ((((kc * 4 + g) ^ (l16 & 7)) << 3))]);
    short8 bv1 = *reinterpret_cast<short8*>(
        &vTs[(16 + l16) * 256 + ((((kc * 4 + g) ^ (l16 & 7)) << 3))]);
    __builtin_amdgcn_s_setprio(1);
    oacc[0][0] = __builtin_amdgcn_mfma_f32_16x16x32_bf16(pa0, bv0, oacc[0][0], 0, 0, 0);
    oacc[0][1] = __builtin_amdgcn_mfma_f32_16x16x32_bf16(pa0, bv1, oacc[0][1], 0, 0, 0);
    oacc[1][0] = __builtin_amdgcn_mfma_f32_16x16x32_bf16(pa1, bv0, oacc[1][0], 0, 0, 0);
    oacc[1][1] = __builtin_amdgcn_mfma_f32_16x16x32_bf16(pa1, bv1, oacc[1][1], 0, 0, 0);
    oaccL[0]   = __builtin_amdgcn_mfma_f32_16x16x32_bf16(pa0, ones8, oaccL[0], 0, 0, 0);
    oaccL[1]   = __builtin_amdgcn_mfma_f32_16x16x32_bf16(pa1, ones8, oaccL[1], 0, 0, 0);
    __builtin_amdgcn_s_setprio(0);
  }

  // ---- normalize (lsum already in-lane via ones-MFMA), bounce O, store ----
  float i0[4], i1[4];
#pragma unroll
  for (int j = 0; j < 4; ++j) {
    i0[j] = __builtin_amdgcn_rcpf(oaccL[0][j]);
    i1[j] = __builtin_amdgcn_rcpf(oaccL[1][j]);
  }
  short* ob = xs + w * 1024;   // own wave's 32x32 region, dead after bq load
  const int u0 = (((l16 >> 3) ^ g) << 3) + (l16 & 7);
  const int u1 = ((((l16 >> 3) | 2) ^ g) << 3) + (l16 & 7);
  {
    const u32 a01 = cvt_pk_bf16(oacc[0][0][0] * i0[0], oacc[0][0][1] * i0[1]);
    const u32 a23 = cvt_pk_bf16(oacc[0][0][2] * i0[2], oacc[0][0][3] * i0[3]);
    const u32 b01 = cvt_pk_bf16(oacc[0][1][0] * i0[0], oacc[0][1][1] * i0[1]);
    const u32 b23 = cvt_pk_bf16(oacc[0][1][2] * i0[2], oacc[0][1][3] * i0[3]);
    const u32 c01 = cvt_pk_bf16(oacc[1][0][0] * i1[0], oacc[1][0][1] * i1[1]);
    const u32 c23 = cvt_pk_bf16(oacc[1][0][2] * i1[2], oacc[1][0][3] * i1[3]);
    const u32 d01 = cvt_pk_bf16(oacc[1][1][0] * i1[0], oacc[1][1][1] * i1[1]);
    const u32 d23 = cvt_pk_bf16(oacc[1][1][2] * i1[2], oacc[1][1][3] * i1[3]);
    const int r0 = (g << 2) * 32;
    ob[r0 + u0]       = (short)a01;  ob[r0 + 32 + u0]  = (short)(a01 >> 16);
    ob[r0 + 64 + u0]  = (short)a23;  ob[r0 + 96 + u0]  = (short)(a23 >> 16);
    ob[r0 + u1]       = (short)b01;  ob[r0 + 32 + u1]  = (short)(b01 >> 16);
    ob[r0 + 64 + u1]  = (short)b23;  ob[r0 + 96 + u1]  = (short)(b23 >> 16);
    const int r1 = r0 + 512;
    ob[r1 + u0]       = (short)c01;  ob[r1 + 32 + u0]  = (short)(c01 >> 16);
    ob[r1 + 64 + u0]  = (short)c23;  ob[r1 + 96 + u0]  = (short)(c23 >> 16);
    ob[r1 + u1]       = (short)d01;  ob[r1 + 32 + u1]  = (short)(d01 >> 16);
    ob[r1 + 64 + u1]  = (short)d23;  ob[r1 + 96 + u1]  = (short)(d23 >> 16);
  }
  // own-wave region: no barrier needed (compiler orders ds_write->ds_read)
  unsigned short* aw = attn_out + (size_t)(b * 256 + w * 32) * 512 + h * 32;
#pragma unroll
  for (int i = 0; i < 2; ++i) {
    const int r = i * 16 + (l >> 2);
    const int cu = l & 3;
    const int su = cu ^ ((r >> 2) & 3);
    short8 vv = *reinterpret_cast<short8*>(&ob[r * 32 + (su << 3)]);
    *reinterpret_cast<short8*>(aw + (size_t)r * 512 + (cu << 3)) = vv;
  }
}

// K2: out = attn @ proj_wT^T + proj_b  (2-buf, issue-after-barrier counted scheme)
__global__ __launch_bounds__(256)
void proj_kernel(const unsigned short* __restrict__ A,    // [65536][512] bf16
                 const unsigned short* __restrict__ BT,   // [512][512] bf16
                 const float* __restrict__ proj_b,
                 float* __restrict__ out) {
  __shared__ short As[2][4096];
  __shared__ short Bs[2][4096];
  const int bid0 = blockIdx.x;                      // 0..2047
  const int swz = ((bid0 & 7) << 8) | (bid0 >> 3);  // bijective: 2048 = 8*256
  const int m0 = (swz >> 2) << 7;
  const int n0 = (swz & 3) << 7;
  const int tid = threadIdx.x;
  const int w = tid >> 6, l = tid & 63, l16 = l & 15, g = l >> 4;
  const int wr = w >> 1, wc = w & 1;
  const int gsw8 = (g ^ ((l16 >> 1) & 3)) << 3;
  const int lrow = l >> 2;
  const int lcol = (((l & 3) ^ ((l >> 3) & 3)) << 3);

  const unsigned short* asrc0 = A + (size_t)(m0 + w * 16 + lrow) * 512 + lcol;
  const unsigned short* asrc1 = asrc0 + (size_t)64 * 512;
  const unsigned short* bsrc0 = BT + (size_t)(n0 + w * 16 + lrow) * 512 + lcol;
  const unsigned short* bsrc1 = bsrc0 + (size_t)64 * 512;

  f32x4v acc[4][4];
#pragma unroll
  for (int mt = 0; mt < 4; ++mt)
#pragma unroll
    for (int nt = 0; nt < 4; ++nt) acc[mt][nt] = (f32x4v)(0.0f);

  auto stage = [&](int t, int bufi) {
    const int k0 = t << 5;
    GLOAD16(asrc0 + k0, As[bufi] + w * 512);
    GLOAD16(asrc1 + k0, As[bufi] + (4 + w) * 512);
    GLOAD16(bsrc0 + k0, Bs[bufi] + w * 512);
    GLOAD16(bsrc1 + k0, Bs[bufi] + (4 + w) * 512);
  };
  stage(0, 0);
#pragma unroll
  for (int t = 0; t < 16; ++t) {
    asm volatile("s_waitcnt vmcnt(0)" ::: "memory");
    __builtin_amdgcn_sched_barrier(0);
    __builtin_amdgcn_s_barrier();
    __builtin_amdgcn_sched_barrier(0);
    if (t < 15) stage(t + 1, (t + 1) & 1);
    const int cur = t & 1;
    short8 af[4], bfr[4];
#pragma unroll
    for (int mt = 0; mt < 4; ++mt)
      af[mt] = *reinterpret_cast<short8*>(&As[cur][(wr * 64 + mt * 16 + l16) * 32 + gsw8]);
#pragma unroll
    for (int nt = 0; nt < 4; ++nt)
      bfr[nt] = *reinterpret_cast<short8*>(&Bs[cur][(wc * 64 + nt * 16 + l16) * 32 + gsw8]);
#pragma unroll
    for (int mt = 0; mt < 4; ++mt)
#pragma unroll
      for (int nt = 0; nt < 4; ++nt)
        acc[mt][nt] = __builtin_amdgcn_mfma_f32_16x16x32_bf16(af[mt], bfr[nt], acc[mt][nt], 0, 0, 0);
  }
#pragma unroll
  for (int nt = 0; nt < 4; ++nt) {
    const int col = n0 + wc * 64 + nt * 16 + l16;
    const float pb = proj_b[col];
#pragma unroll
    for (int mt = 0; mt < 4; ++mt)
#pragma unroll
      for (int j = 0; j < 4; ++j)
        out[(size_t)(m0 + wr * 64 + mt * 16 + g * 4 + j) * 512 + col] = acc[mt][nt][j] + pb;
  }
}

extern "C" void kernel_launch(void* const* d_in, const int* in_sizes, int n_in,
                              void* d_out, int out_size, void* d_ws, size_t ws_size,
                              hipStream_t stream) {
  const float* x      = (const float*)d_in[0];
  const float* temb   = (const float*)d_in[1];
  const float* qkv_w  = (const float*)d_in[2];
  const float* qkv_b  = (const float*)d_in[3];
  const float* temb_w = (const float*)d_in[4];
  const float* temb_b = (const float*)d_in[5];
  const float* rpb    = (const float*)d_in[6];
  const float* proj_w = (const float*)d_in[7];
  const float* proj_b = (const float*)d_in[8];
  float* out = (float*)d_out;

  char* ws = (char*)d_ws;
  float* tm               = (float*)ws;                                  // 1,572,864 B
  unsigned short* xb16    = (unsigned short*)(ws + 1572864);             // 67,108,864 B
  unsigned short* qkv_wT  = (unsigned short*)(ws + 1572864 + 67108864);  // 1,572,864 B
  unsigned short* proj_wT = (unsigned short*)(ws + 1572864 + 67108864 + 1572864);  // 524,288 B
  unsigned short* attn_ws = (unsigned short*)(ws + 1572864 + 67108864 + 1572864 + 524288); // 67,108,864 B

  prep_kernel<<<1536, 512, 0, stream>>>(temb, temb_w, temb_b, qkv_b, tm,
                                        x, (unsigned*)xb16,
                                        qkv_w, qkv_wT, proj_w, proj_wT);
  fused_attn_kernel<<<B_ * H_, 512, 0, stream>>>(xb16, qkv_wT, rpb, tm, attn_ws);
  proj_kernel<<<2048, 256, 0, stream>>>(attn_ws, proj_wT, proj_b, out);
}